// Round 3
// baseline (152.351 us; speedup 1.0000x reference)
//
#include <hip/hip_runtime.h>
#include <hip/hip_bf16.h>

#define NROWS   131072
#define DDIM    64
#define KCODES  512
#define NBLOCKS 1024

// big-ws float offsets
#define WS_WT_OFS   0       // 32768 floats (wT[k][d])
#define WS_PART_BIG 32768   // 1024 floats

__global__ void vqf_prep_wt(const float* __restrict__ w, float* __restrict__ wT) {
  int g = blockIdx.x * 256 + threadIdx.x;  // 0..32767 ; g = k*64 + d
  wT[g] = w[(g & 63) * KCODES + (g >> 6)];
}

template <int USE_WT, int LOSS_ATOMIC>
__global__ __launch_bounds__(256) void vqf_main(
    const float* __restrict__ x, const float* __restrict__ w,
    const float* __restrict__ wT,
    float* __restrict__ out_idx, float* __restrict__ out_zq,
    float* __restrict__ out_ze, float* __restrict__ lossOut) {
  __shared__ float xT[4][32 * 64];                         // per-wave x tile [d][row]
  __shared__ float wtile[64 * 64];                         // w code-tile [d][kk]
  __shared__ float __attribute__((aligned(16))) sq_s[64];  // per-tile wsq
  __shared__ float sumf_s[4][32];
  __shared__ int   idx_s[4][32];
  __shared__ float lsum_s[4];

  const int tid = threadIdx.x;
  const int wv = tid >> 6;
  const int lane = tid & 63;
  const int r = lane >> 3;   // row-group 0..7 (4 rows)
  const int c = lane & 7;    // code-group 0..7 (8 codes)
  const int rowBase = (blockIdx.x * 4 + wv) * 32;
  const float* xblk = x + (size_t)rowBase * DDIM;

  // ---- stage x tile transposed ----
#pragma unroll
  for (int j = 0; j < 8; ++j) {
    int off = j * 256 + lane * 4;
    float4 v = *(const float4*)(xblk + off);
    int row = off >> 6, d0 = off & 63;
    xT[wv][(d0 + 0) * 32 + row] = v.x;
    xT[wv][(d0 + 1) * 32 + row] = v.y;
    xT[wv][(d0 + 2) * 32 + row] = v.z;
    xT[wv][(d0 + 3) * 32 + row] = v.w;
  }
  __syncthreads();

  // ---- sumf per row: numpy pairwise 8-accumulator scheme (contiguous axis) ----
  if (lane < 32) {
    float rr[8];
#pragma unroll
    for (int j = 0; j < 8; ++j) {
      float v = xT[wv][j * 32 + lane];
      rr[j] = __fmul_rn(v, v);
    }
#pragma unroll
    for (int blk = 1; blk < 8; ++blk)
#pragma unroll
      for (int j = 0; j < 8; ++j) {
        float v = xT[wv][(blk * 8 + j) * 32 + lane];
        rr[j] = __fadd_rn(rr[j], __fmul_rn(v, v));
      }
    float s01 = __fadd_rn(rr[0], rr[1]);
    float s23 = __fadd_rn(rr[2], rr[3]);
    float s45 = __fadd_rn(rr[4], rr[5]);
    float s67 = __fadd_rn(rr[6], rr[7]);
    sumf_s[wv][lane] = __fadd_rn(__fadd_rn(s01, s23), __fadd_rn(s45, s67));
  }

  float minv[4] = {3.4e38f, 3.4e38f, 3.4e38f, 3.4e38f};
  int mink[4] = {0, 0, 0, 0};

  for (int ct = 0; ct < 8; ++ct) {
    // stage w code-tile (block-cooperative, coalesced)
#pragma unroll
    for (int j = 0; j < 4; ++j) {
      int off = j * 1024 + tid * 4;
      int d0 = off >> 6, kk = off & 63;
      *(float4*)&wtile[off] = *(const float4*)&w[d0 * KCODES + ct * 64 + kk];
    }
    __syncthreads();

    // wsq: numpy axis-0 reduce = sequential over d (wave 0 computes)
    if (tid < 64) {
      float v0 = wtile[tid];
      float s = __fmul_rn(v0, v0);
      for (int d = 1; d < 64; ++d) {
        float v = wtile[d * 64 + tid];
        s = __fadd_rn(s, __fmul_rn(v, v));
      }
      sq_s[tid] = s;
    }

    float acc[4][8];
#pragma unroll
    for (int i = 0; i < 4; ++i)
#pragma unroll
      for (int j = 0; j < 8; ++j) acc[i][j] = 0.f;

    // sequential-d single-accumulator FMA dot: matches BLAS sgemm K-order
#pragma unroll 4
    for (int d = 0; d < DDIM; ++d) {
      float4 a4 = *(const float4*)&xT[wv][d * 32 + r * 4];
      float4 b0 = *(const float4*)&wtile[d * 64 + c * 8];
      float4 b1 = *(const float4*)&wtile[d * 64 + c * 8 + 4];
      float a[4] = {a4.x, a4.y, a4.z, a4.w};
      float b[8] = {b0.x, b0.y, b0.z, b0.w, b1.x, b1.y, b1.z, b1.w};
#pragma unroll
      for (int i = 0; i < 4; ++i)
#pragma unroll
        for (int j = 0; j < 8; ++j)
          acc[i][j] = __builtin_fmaf(a[i], b[j], acc[i][j]);
    }
    __syncthreads();  // wtile consumed; sq_s visible to all

    // distances: numpy tree (sumf - 2*dot) + wsq, per-op rounding
#pragma unroll
    for (int i = 0; i < 4; ++i) {
      float sf = sumf_s[wv][r * 4 + i];
#pragma unroll
      for (int j = 0; j < 8; ++j) {
        float dist = __fadd_rn(__fsub_rn(sf, __fmul_rn(2.0f, acc[i][j])), sq_s[c * 8 + j]);
        int k = ct * 64 + c * 8 + j;
        if (dist < minv[i]) { minv[i] = dist; mink[i] = k; }  // strict <: first index wins
      }
    }
  }

  // cross-lane argmin over the 8 code-groups (tie -> smaller k)
#pragma unroll
  for (int i = 0; i < 4; ++i) {
    float v = minv[i];
    int kk = mink[i];
    for (int s = 1; s < 8; s <<= 1) {
      float ov = __shfl_xor(v, s);
      int ok = __shfl_xor(kk, s);
      if (ov < v || (ov == v && ok < kk)) { v = ov; kk = ok; }
    }
    if (c == 0) idx_s[wv][r * 4 + i] = kk;
  }
  // idx_s[wv] produced and consumed by the same wave

  // ---- epilogue (ALL fp32 stores): z_q_st, z_e, loss partial, indices ----
  float lsum = 0.f;
  for (int rowi = 0; rowi < 32; ++rowi) {
    int k = idx_s[wv][rowi];
    size_t go = (size_t)(rowBase + rowi) * DDIM + lane;
    float xv = xblk[rowi * DDIM + lane];
    float wvv = USE_WT ? wT[k * DDIM + lane] : w[lane * KCODES + k];
    // z_q_st = z_e + (z_q - z_e), per-op rounding as numpy
    out_zq[go] = __fadd_rn(xv, __fsub_rn(wvv, xv));
    out_ze[go] = xv;
    float dd = __fsub_rn(wvv, xv);
    lsum = __builtin_fmaf(dd, dd, lsum);
  }
#pragma unroll
  for (int s = 1; s < 64; s <<= 1) lsum += __shfl_xor(lsum, s);
  if (lane == 0) lsum_s[wv] = lsum;
  __syncthreads();
  if (tid == 0) {
    float part = __fadd_rn(__fadd_rn(__fadd_rn(lsum_s[0], lsum_s[1]), lsum_s[2]), lsum_s[3]);
    if (LOSS_ATOMIC) atomicAdd(lossOut, part);
    else lossOut[blockIdx.x] = part;
  }
  if (lane < 32)
    out_idx[rowBase + lane] = (float)idx_s[wv][lane];
}

// loss = 2 * sum / (N*D) = sum * 2^-22
__global__ void vqf_loss(const float* __restrict__ part, int npart,
                         float* __restrict__ out_loss) {
  float s = 0.f;
  for (int i = threadIdx.x; i < npart; i += 64) s += part[i];
#pragma unroll
  for (int t = 1; t < 64; t <<= 1) s += __shfl_xor(s, t);
  if (threadIdx.x == 0) out_loss[0] = s * (1.0f / 4194304.0f);
}

extern "C" void kernel_launch(void* const* d_in, const int* in_sizes, int n_in,
                              void* d_out, int out_size, void* d_ws, size_t ws_size,
                              hipStream_t stream) {
  const float* x = (const float*)d_in[0];
  const float* w = (const float*)d_in[1];
  float* ob = (float*)d_out;  // fp32 output buffer (fp32 reference -> float*)
  float* out_idx = ob;
  float* out_zq = ob + NROWS;
  float* out_ze = out_zq + (size_t)NROWS * DDIM;
  float* out_loss = out_ze + (size_t)NROWS * DDIM;
  float* wsf = (float*)d_ws;

  const size_t needBig = (size_t)(32768 + 1024) * sizeof(float);  // 135168 B
  if (ws_size >= needBig) {
    vqf_prep_wt<<<128, 256, 0, stream>>>(w, wsf + WS_WT_OFS);
    vqf_main<1, 0><<<NBLOCKS, 256, 0, stream>>>(x, w, wsf + WS_WT_OFS, out_idx,
                                                out_zq, out_ze, wsf + WS_PART_BIG);
    vqf_loss<<<1, 64, 0, stream>>>(wsf + WS_PART_BIG, NBLOCKS, out_loss);
  } else if (ws_size >= NBLOCKS * sizeof(float)) {
    vqf_main<0, 0><<<NBLOCKS, 256, 0, stream>>>(x, w, nullptr, out_idx,
                                                out_zq, out_ze, wsf);
    vqf_loss<<<1, 64, 0, stream>>>(wsf, NBLOCKS, out_loss);
  } else {
    hipMemsetAsync(d_ws, 0, sizeof(float), stream);
    vqf_main<0, 1><<<NBLOCKS, 256, 0, stream>>>(x, w, nullptr, out_idx,
                                                out_zq, out_ze, wsf);
    vqf_loss<<<1, 64, 0, stream>>>(wsf, 1, out_loss);
  }
}